// Round 1
// baseline (920.292 us; speedup 1.0000x reference)
//
#include <hip/hip_runtime.h>

// Problem constants (from reference setup_inputs)
#define N_NODES 50000
#define D_FEAT  256
#define G_GROUPS 4
#define E_EDGES 800000
#define DG      64          // D_FEAT / G_GROUPS

// ---------------------------------------------------------------------------
// Stage 1: per-group SpMM scatter-add.
// One wave (64 lanes) per edge; lane = feature index within the group's
// 64-wide column block. Coalesced 256B gather of x[col, g*64+lane], then
// 64 contiguous float atomicAdds into tmp[row, g*64+lane].
// ---------------------------------------------------------------------------
__global__ __launch_bounds__(256) void spmm_scatter_kernel(
    const float* __restrict__ x,
    const int*   __restrict__ edge_row,
    const int*   __restrict__ edge_col,
    const float* __restrict__ edge_val,
    float*       __restrict__ tmp)
{
    const long long gtid = (long long)blockIdx.x * blockDim.x + threadIdx.x;
    const int wave = (int)(gtid >> 6);           // edge index across all groups
    const int lane = threadIdx.x & 63;
    if (wave >= G_GROUPS * E_EDGES) return;

    const int g = wave / E_EDGES;                // group
    const int row = edge_row[wave];
    const int col = edge_col[wave];
    const float val = edge_val[wave];

    const float xv = x[(long long)col * D_FEAT + g * DG + lane];
    atomicAdd(&tmp[(long long)row * D_FEAT + g * DG + lane], val * xv);
}

// ---------------------------------------------------------------------------
// Stage 2: C[N,256] = tmp[N,256] @ W[256,256] + bias
// f32 vector-ALU tiled GEMM: 64x64 tile, BK=64, 256 threads, 4x4 acc/thread.
// A tile stored k-major in LDS so both fragment reads are float4 (b128).
// ---------------------------------------------------------------------------
#define BM 64
#define BN 64
#define BK 64

__global__ __launch_bounds__(256) void gemm_bias_kernel(
    const float* __restrict__ A,      // tmp [N, 256]
    const float* __restrict__ W,      // [256, 256]
    const float* __restrict__ bias,   // [256]
    float*       __restrict__ C)      // [N, 256]
{
    __shared__ float As[BK][BM + 4];  // [k][m], +4 pad (keeps 16B alignment)
    __shared__ float Ws[BK][BN + 4];  // [k][n]

    const int tid = threadIdx.x;
    const int tx = tid & 15;          // 16 col-groups of 4
    const int ty = tid >> 4;          // 16 row-groups of 4
    const int row0 = blockIdx.x * BM;
    const int col0 = blockIdx.y * BN;

    float acc[4][4] = {};

    for (int k0 = 0; k0 < D_FEAT; k0 += BK) {
        // Load A tile: 64 rows x 64 k = 1024 float4; 4 float4 per thread.
        // Stored transposed (k-major) via 4 scalar LDS writes each.
        #pragma unroll
        for (int l = 0; l < 4; ++l) {
            const int linear = tid + l * 256;   // float4 slot in [0,1024)
            const int ar = linear >> 4;         // row within tile
            const int ac = (linear & 15) << 2;  // k within tile
            float4 v = make_float4(0.f, 0.f, 0.f, 0.f);
            const int gr = row0 + ar;
            if (gr < N_NODES)
                v = *(const float4*)&A[(long long)gr * D_FEAT + k0 + ac];
            As[ac + 0][ar] = v.x;
            As[ac + 1][ar] = v.y;
            As[ac + 2][ar] = v.z;
            As[ac + 3][ar] = v.w;
        }
        // Load W tile: 64 k x 64 cols, row-major float4 stores.
        #pragma unroll
        for (int l = 0; l < 4; ++l) {
            const int linear = tid + l * 256;
            const int wr = linear >> 4;         // k within tile
            const int wc = (linear & 15) << 2;  // col within tile
            const float4 v = *(const float4*)&W[(long long)(k0 + wr) * D_FEAT + col0 + wc];
            *(float4*)&Ws[wr][wc] = v;
        }
        __syncthreads();

        #pragma unroll
        for (int k = 0; k < BK; ++k) {
            const float4 a4 = *(const float4*)&As[k][ty * 4];
            const float4 b4 = *(const float4*)&Ws[k][tx * 4];
            const float a[4] = {a4.x, a4.y, a4.z, a4.w};
            const float b[4] = {b4.x, b4.y, b4.z, b4.w};
            #pragma unroll
            for (int i = 0; i < 4; ++i)
                #pragma unroll
                for (int j = 0; j < 4; ++j)
                    acc[i][j] += a[i] * b[j];
        }
        __syncthreads();
    }

    // Epilogue: add bias, float4 stores.
    const float4 b4 = *(const float4*)&bias[col0 + tx * 4];
    #pragma unroll
    for (int i = 0; i < 4; ++i) {
        const int gr = row0 + ty * 4 + i;
        if (gr >= N_NODES) continue;
        float4 v;
        v.x = acc[i][0] + b4.x;
        v.y = acc[i][1] + b4.y;
        v.z = acc[i][2] + b4.z;
        v.w = acc[i][3] + b4.w;
        *(float4*)&C[(long long)gr * D_FEAT + col0 + tx * 4] = v;
    }
}

extern "C" void kernel_launch(void* const* d_in, const int* in_sizes, int n_in,
                              void* d_out, int out_size, void* d_ws, size_t ws_size,
                              hipStream_t stream)
{
    const float* x        = (const float*)d_in[0];
    const int*   edge_row = (const int*)d_in[1];
    const int*   edge_col = (const int*)d_in[2];
    const float* edge_val = (const float*)d_in[3];
    const float* weight   = (const float*)d_in[4];
    const float* bias     = (const float*)d_in[5];
    float* out = (float*)d_out;
    float* tmp = (float*)d_ws;   // [N, 256] accumulator

    const size_t tmp_bytes = (size_t)N_NODES * D_FEAT * sizeof(float);
    hipMemsetAsync(tmp, 0, tmp_bytes, stream);

    // Stage 1: one wave per edge -> G*E waves, 4 waves per 256-thread block.
    const long long total_threads = (long long)G_GROUPS * E_EDGES * 64;
    const int blocks1 = (int)((total_threads + 255) / 256);
    spmm_scatter_kernel<<<blocks1, 256, 0, stream>>>(x, edge_row, edge_col, edge_val, tmp);

    // Stage 2: GEMM + bias
    dim3 grid2((N_NODES + BM - 1) / BM, D_FEAT / BN);
    gemm_bias_kernel<<<grid2, 256, 0, stream>>>(tmp, weight, bias, out);
}

// Round 2
// 881.166 us; speedup vs baseline: 1.0444x; 1.0444x over previous
//
#include <hip/hip_runtime.h>

#define N_NODES 50000
#define D_FEAT  256
#define G_GROUPS 4
#define E_EDGES 800000
#define DG      64
#define M_SEG   (G_GROUPS * N_NODES)        // 200000 (g,row) segments
#define TOT_E   (G_GROUPS * E_EDGES)        // 3200000 edges

// ---------------------------------------------------------------------------
// Fallback (round-1) atomic SpMM — used only if ws_size is too small.
// ---------------------------------------------------------------------------
__global__ __launch_bounds__(256) void spmm_scatter_kernel(
    const float* __restrict__ x, const int* __restrict__ edge_row,
    const int* __restrict__ edge_col, const float* __restrict__ edge_val,
    float* __restrict__ tmp)
{
    const long long gtid = (long long)blockIdx.x * blockDim.x + threadIdx.x;
    const int wave = (int)(gtid >> 6);
    const int lane = threadIdx.x & 63;
    if (wave >= TOT_E) return;
    const int g = wave / E_EDGES;
    const int row = edge_row[wave];
    const int col = edge_col[wave];
    const float val = edge_val[wave];
    const float xv = x[(long long)col * D_FEAT + g * DG + lane];
    atomicAdd(&tmp[(long long)row * D_FEAT + g * DG + lane], val * xv);
}

// ---------------------------------------------------------------------------
// CSR build: histogram -> 3-kernel exclusive scan -> scatter pairs
// ---------------------------------------------------------------------------
__global__ __launch_bounds__(256) void hist_kernel(
    const int* __restrict__ edge_row, int* __restrict__ cnt)
{
    const int i = blockIdx.x * 256 + threadIdx.x;
    if (i >= TOT_E) return;
    const int g = i / E_EDGES;
    atomicAdd(&cnt[g * N_NODES + edge_row[i]], 1);
}

// block sums: each block reduces 1024 counters
__global__ __launch_bounds__(256) void scan_block_sums(
    const int* __restrict__ cnt, int* __restrict__ bsum)
{
    __shared__ int sdata[256];
    const int t = threadIdx.x;
    const int base = blockIdx.x * 1024 + t * 4;
    int s = 0;
    #pragma unroll
    for (int i = 0; i < 4; ++i) {
        const int idx = base + i;
        s += (idx < M_SEG) ? cnt[idx] : 0;
    }
    sdata[t] = s;
    __syncthreads();
    for (int off = 128; off > 0; off >>= 1) {
        if (t < off) sdata[t] += sdata[t + off];
        __syncthreads();
    }
    if (t == 0) bsum[blockIdx.x] = sdata[0];
}

// exclusive scan of block sums (nb <= 256), single block
__global__ __launch_bounds__(256) void scan_offsets_kernel(
    const int* __restrict__ bsum, int* __restrict__ boff, int nb)
{
    __shared__ int sdata[256];
    const int t = threadIdx.x;
    const int own = (t < nb) ? bsum[t] : 0;
    sdata[t] = own;
    __syncthreads();
    for (int off = 1; off < 256; off <<= 1) {
        const int v = (t >= off) ? sdata[t - off] : 0;
        __syncthreads();
        sdata[t] += v;
        __syncthreads();
    }
    if (t < nb) boff[t] = sdata[t] - own;   // exclusive
}

// final scan: per-element exclusive offsets = block-local scan + block offset
__global__ __launch_bounds__(256) void scan_final_kernel(
    const int* __restrict__ cnt, const int* __restrict__ boff,
    int* __restrict__ offs, int* __restrict__ cursor)
{
    __shared__ int sdata[256];
    const int t = threadIdx.x;
    const int base = blockIdx.x * 1024 + t * 4;
    int v[4];
    int s = 0;
    #pragma unroll
    for (int i = 0; i < 4; ++i) {
        const int idx = base + i;
        v[i] = (idx < M_SEG) ? cnt[idx] : 0;
        s += v[i];
    }
    const int own = s;
    sdata[t] = s;
    __syncthreads();
    for (int off = 1; off < 256; off <<= 1) {
        const int u = (t >= off) ? sdata[t - off] : 0;
        __syncthreads();
        sdata[t] += u;
        __syncthreads();
    }
    int run = sdata[t] - own + boff[blockIdx.x];
    #pragma unroll
    for (int i = 0; i < 4; ++i) {
        const int idx = base + i;
        if (idx < M_SEG) { offs[idx] = run; cursor[idx] = run; }
        run += v[i];
    }
}

__global__ __launch_bounds__(256) void build_pairs_kernel(
    const int* __restrict__ edge_row, const int* __restrict__ edge_col,
    const float* __restrict__ edge_val, int* __restrict__ cursor,
    int2* __restrict__ pairs)
{
    const int i = blockIdx.x * 256 + threadIdx.x;
    if (i >= TOT_E) return;
    const int g = i / E_EDGES;
    const int pos = atomicAdd(&cursor[g * N_NODES + edge_row[i]], 1);
    pairs[pos] = make_int2(edge_col[i], __float_as_int(edge_val[i]));
}

// ---------------------------------------------------------------------------
// Gather-reduce SpMM: one wave per (g,row); lane = feature in group block.
// Wave-uniform pair loads (HW broadcast) + coalesced 256B gathers; one store.
// ---------------------------------------------------------------------------
__global__ __launch_bounds__(256) void spmm_csr_kernel(
    const float* __restrict__ x, const int2* __restrict__ pairs,
    const int* __restrict__ offs, float* __restrict__ tmp)
{
    const int w = (blockIdx.x * 256 + threadIdx.x) >> 6;   // 0 .. M_SEG-1 exact
    const int lane = threadIdx.x & 63;
    const int g = w / N_NODES;
    const int row = w - g * N_NODES;

    const int start = offs[w];
    const int end = (w + 1 < M_SEG) ? offs[w + 1] : TOT_E;

    const float* __restrict__ xb = x + g * DG + lane;
    float acc = 0.f;
    for (int e = start; e < end; ++e) {
        const int2 pr = pairs[e];                 // wave-uniform -> broadcast
        acc += __int_as_float(pr.y) * xb[(long long)pr.x * D_FEAT];
    }
    tmp[(long long)row * D_FEAT + g * DG + lane] = acc;
}

// ---------------------------------------------------------------------------
// Stage 2: C = tmp @ W + bias (unchanged f32 tiled GEMM)
// ---------------------------------------------------------------------------
#define BM 64
#define BN 64
#define BK 64

__global__ __launch_bounds__(256) void gemm_bias_kernel(
    const float* __restrict__ A, const float* __restrict__ W,
    const float* __restrict__ bias, float* __restrict__ C)
{
    __shared__ float As[BK][BM + 4];
    __shared__ float Ws[BK][BN + 4];

    const int tid = threadIdx.x;
    const int tx = tid & 15;
    const int ty = tid >> 4;
    const int row0 = blockIdx.x * BM;
    const int col0 = blockIdx.y * BN;

    float acc[4][4] = {};

    for (int k0 = 0; k0 < D_FEAT; k0 += BK) {
        #pragma unroll
        for (int l = 0; l < 4; ++l) {
            const int linear = tid + l * 256;
            const int ar = linear >> 4;
            const int ac = (linear & 15) << 2;
            float4 v = make_float4(0.f, 0.f, 0.f, 0.f);
            const int gr = row0 + ar;
            if (gr < N_NODES)
                v = *(const float4*)&A[(long long)gr * D_FEAT + k0 + ac];
            As[ac + 0][ar] = v.x;
            As[ac + 1][ar] = v.y;
            As[ac + 2][ar] = v.z;
            As[ac + 3][ar] = v.w;
        }
        #pragma unroll
        for (int l = 0; l < 4; ++l) {
            const int linear = tid + l * 256;
            const int wr = linear >> 4;
            const int wc = (linear & 15) << 2;
            *(float4*)&Ws[wr][wc] =
                *(const float4*)&W[(long long)(k0 + wr) * D_FEAT + col0 + wc];
        }
        __syncthreads();

        #pragma unroll
        for (int k = 0; k < BK; ++k) {
            const float4 a4 = *(const float4*)&As[k][ty * 4];
            const float4 b4 = *(const float4*)&Ws[k][tx * 4];
            const float a[4] = {a4.x, a4.y, a4.z, a4.w};
            const float b[4] = {b4.x, b4.y, b4.z, b4.w};
            #pragma unroll
            for (int i = 0; i < 4; ++i)
                #pragma unroll
                for (int j = 0; j < 4; ++j)
                    acc[i][j] += a[i] * b[j];
        }
        __syncthreads();
    }

    const float4 b4 = *(const float4*)&bias[col0 + tx * 4];
    #pragma unroll
    for (int i = 0; i < 4; ++i) {
        const int gr = row0 + ty * 4 + i;
        if (gr >= N_NODES) continue;
        float4 v;
        v.x = acc[i][0] + b4.x;
        v.y = acc[i][1] + b4.y;
        v.z = acc[i][2] + b4.z;
        v.w = acc[i][3] + b4.w;
        *(float4*)&C[(long long)gr * D_FEAT + col0 + tx * 4] = v;
    }
}

// ---------------------------------------------------------------------------
extern "C" void kernel_launch(void* const* d_in, const int* in_sizes, int n_in,
                              void* d_out, int out_size, void* d_ws, size_t ws_size,
                              hipStream_t stream)
{
    const float* x        = (const float*)d_in[0];
    const int*   edge_row = (const int*)d_in[1];
    const int*   edge_col = (const int*)d_in[2];
    const float* edge_val = (const float*)d_in[3];
    const float* weight   = (const float*)d_in[4];
    const float* bias     = (const float*)d_in[5];
    float* out = (float*)d_out;

    // workspace layout (256B-aligned slices)
    char* p = (char*)d_ws;
    auto alloc = [&](size_t bytes) {
        char* r = p;
        p += (bytes + 255) & ~(size_t)255;
        return r;
    };
    float* tmp    = (float*)alloc((size_t)N_NODES * D_FEAT * sizeof(float)); // 51.2 MB
    int*   cnt    = (int*)  alloc((size_t)M_SEG * sizeof(int));
    int*   offs   = (int*)  alloc((size_t)M_SEG * sizeof(int));
    int*   cursor = (int*)  alloc((size_t)M_SEG * sizeof(int));
    int*   bsum   = (int*)  alloc(1024);
    int*   boff   = (int*)  alloc(1024);
    int2*  pairs  = (int2*) alloc((size_t)TOT_E * sizeof(int2));             // 25.6 MB
    const size_t needed = (size_t)(p - (char*)d_ws);

    const int nb_seg = (M_SEG + 1023) / 1024;   // 196 scan blocks

    if (ws_size >= needed) {
        hipMemsetAsync(cnt, 0, (size_t)M_SEG * sizeof(int), stream);
        hist_kernel<<<(TOT_E + 255) / 256, 256, 0, stream>>>(edge_row, cnt);
        scan_block_sums<<<nb_seg, 256, 0, stream>>>(cnt, bsum);
        scan_offsets_kernel<<<1, 256, 0, stream>>>(bsum, boff, nb_seg);
        scan_final_kernel<<<nb_seg, 256, 0, stream>>>(cnt, boff, offs, cursor);
        build_pairs_kernel<<<(TOT_E + 255) / 256, 256, 0, stream>>>(
            edge_row, edge_col, edge_val, cursor, pairs);
        spmm_csr_kernel<<<M_SEG * 64 / 256, 256, 0, stream>>>(x, pairs, offs, tmp);
    } else {
        // fallback: atomic scatter path (round 1)
        hipMemsetAsync(tmp, 0, (size_t)N_NODES * D_FEAT * sizeof(float), stream);
        const long long total_threads = (long long)TOT_E * 64;
        spmm_scatter_kernel<<<(int)((total_threads + 255) / 256), 256, 0, stream>>>(
            x, edge_row, edge_col, edge_val, tmp);
    }

    dim3 grid2((N_NODES + BM - 1) / BM, D_FEAT / BN);
    gemm_bias_kernel<<<grid2, 256, 0, stream>>>(tmp, weight, bias, out);
}

// Round 3
// 624.037 us; speedup vs baseline: 1.4747x; 1.4120x over previous
//
#include <hip/hip_runtime.h>
#include <hip/hip_bf16.h>

#define N_NODES 50000
#define D_FEAT  256
#define G_GROUPS 4
#define E_EDGES 800000
#define DG      64
#define M_SEG   (G_GROUPS * N_NODES)        // 200000 segments
#define TOT_E   (G_GROUPS * E_EDGES)        // 3200000 edges
#define KSUB    4                           // sub-chains per segment (MLP)
#define M_PAD   50048                       // 391 * 128

typedef short bf16x8 __attribute__((ext_vector_type(8)));   // 8 bf16 (4 VGPRs)
typedef float f32x4  __attribute__((ext_vector_type(4)));

__device__ __forceinline__ unsigned short f2bf(float f) {
    unsigned int u = __float_as_uint(f);
    u += 0x7FFF + ((u >> 16) & 1);          // RNE
    return (unsigned short)(u >> 16);
}
__device__ __forceinline__ float bf2f(unsigned short h) {
    return __uint_as_float((unsigned int)h << 16);
}

// ---------------------------------------------------------------------------
// x (f32 [N,256]) -> x_bf (bf16). 8 elems / thread.
// ---------------------------------------------------------------------------
__global__ __launch_bounds__(256) void convert_x_kernel(
    const float* __restrict__ x, unsigned short* __restrict__ xb)
{
    const long long base = ((long long)blockIdx.x * 256 + threadIdx.x) * 8;
    if (base >= (long long)N_NODES * D_FEAT) return;
    const float4 v0 = *(const float4*)&x[base];
    const float4 v1 = *(const float4*)&x[base + 4];
    unsigned short r[8];
    r[0] = f2bf(v0.x); r[1] = f2bf(v0.y); r[2] = f2bf(v0.z); r[3] = f2bf(v0.w);
    r[4] = f2bf(v1.x); r[5] = f2bf(v1.y); r[6] = f2bf(v1.z); r[7] = f2bf(v1.w);
    *(uint4*)&xb[base] = *(const uint4*)r;
}

// W [K=256, N=256] f32 -> Wt [n][k] bf16 (transposed, k-contiguous)
__global__ __launch_bounds__(256) void convert_w_kernel(
    const float* __restrict__ W, unsigned short* __restrict__ Wt)
{
    const int n = blockIdx.x;       // 256 blocks
    const int k = threadIdx.x;      // 256 threads
    Wt[n * D_FEAT + k] = f2bf(W[k * D_FEAT + n]);
}

// ---------------------------------------------------------------------------
// Linked-list build: one returning atomicExch + one contiguous next-write.
// head[seg*KSUB + (e & 3)] chains edges of segment seg.
// ---------------------------------------------------------------------------
__global__ __launch_bounds__(256) void build_ll_kernel(
    const int* __restrict__ edge_row, int* __restrict__ head, int* __restrict__ nxt)
{
    const int i = blockIdx.x * 256 + threadIdx.x;
    if (i >= TOT_E) return;
    const int g = i / E_EDGES;
    const int seg = g * N_NODES + edge_row[i];
    nxt[i] = atomicExch(&head[seg * KSUB + (i & (KSUB - 1))], i);
}

// ---------------------------------------------------------------------------
// Gather SpMM over 4 linked sub-chains per (g,row) wave; bf16 gathers,
// f32 accumulate, bf16 store. All control flow is wave-uniform.
// ---------------------------------------------------------------------------
__global__ __launch_bounds__(256) void spmm_ll_kernel(
    const unsigned short* __restrict__ xb, const int* __restrict__ edge_col,
    const float* __restrict__ edge_val, const int* __restrict__ head,
    const int* __restrict__ nxt, unsigned short* __restrict__ tmpb)
{
    const int w = (blockIdx.x * 256 + threadIdx.x) >> 6;   // segment, exact
    const int lane = threadIdx.x & 63;
    const int g = w / N_NODES;
    const int row = w - g * N_NODES;

    const unsigned short* __restrict__ xcol = xb + g * DG + lane;

    int e0 = head[w * KSUB + 0];
    int e1 = head[w * KSUB + 1];
    int e2 = head[w * KSUB + 2];
    int e3 = head[w * KSUB + 3];

    float acc = 0.f;
    while ((e0 & e1 & e2 & e3) != -1) {
        int c0 = 0, c1 = 0, c2 = 0, c3 = 0;
        float v0 = 0.f, v1 = 0.f, v2 = 0.f, v3 = 0.f;
        int n0 = -1, n1 = -1, n2 = -1, n3 = -1;
        // issue all chain loads first (uniform addresses -> broadcast)
        if (e0 >= 0) { c0 = edge_col[e0]; v0 = edge_val[e0]; n0 = nxt[e0]; }
        if (e1 >= 0) { c1 = edge_col[e1]; v1 = edge_val[e1]; n1 = nxt[e1]; }
        if (e2 >= 0) { c2 = edge_col[e2]; v2 = edge_val[e2]; n2 = nxt[e2]; }
        if (e3 >= 0) { c3 = edge_col[e3]; v3 = edge_val[e3]; n3 = nxt[e3]; }
        // gathers (128B per active chain)
        if (e0 >= 0) acc += v0 * bf2f(xcol[(long long)c0 * D_FEAT]);
        if (e1 >= 0) acc += v1 * bf2f(xcol[(long long)c1 * D_FEAT]);
        if (e2 >= 0) acc += v2 * bf2f(xcol[(long long)c2 * D_FEAT]);
        if (e3 >= 0) acc += v3 * bf2f(xcol[(long long)c3 * D_FEAT]);
        e0 = n0; e1 = n1; e2 = n2; e3 = n3;
    }
    tmpb[(long long)row * D_FEAT + g * DG + lane] = f2bf(acc);
}

// ---------------------------------------------------------------------------
// MFMA GEMM: C[M,256] = tmp_bf @ W + bias.  A: [M_PAD,256] bf16 row-major,
// Bt: [256,256] bf16 n-major/k-contiguous. 128x128 tile, BK=32, 4 waves.
// ---------------------------------------------------------------------------
#define TBK 32
#define LDP 40   // padded LDS row (ushorts): 80B stride spreads all 32 banks

__global__ __launch_bounds__(256) void gemm_mfma_kernel(
    const unsigned short* __restrict__ A, const unsigned short* __restrict__ Bt,
    const float* __restrict__ bias, float* __restrict__ C)
{
    __shared__ unsigned short As[128][LDP];   // 10 KB
    __shared__ unsigned short Bs[128][LDP];   // 10 KB

    const int tid = threadIdx.x;
    const int wid = tid >> 6, lane = tid & 63;
    const int wm = (wid & 1) * 64, wn = (wid >> 1) * 64;
    const int lm = lane & 15, lq = lane >> 4;
    const int row0 = blockIdx.x * 128, col0 = blockIdx.y * 128;

    f32x4 acc[4][4] = {};

    for (int k0 = 0; k0 < D_FEAT; k0 += TBK) {
        // A tile: 128 rows x 32 k; 64B/row = 4 x 16B chunks; 2 chunks/thread
        #pragma unroll
        for (int l = 0; l < 2; ++l) {
            const int chunk = tid + l * 256;     // 0..511
            const int r = chunk >> 2;
            const int c = (chunk & 3) * 8;
            uint4 v = make_uint4(0u, 0u, 0u, 0u);
            const int gr = row0 + r;
            if (gr < N_NODES)
                v = *(const uint4*)&A[(long long)gr * D_FEAT + k0 + c];
            *(uint4*)&As[r][c] = v;
        }
        #pragma unroll
        for (int l = 0; l < 2; ++l) {
            const int chunk = tid + l * 256;
            const int r = chunk >> 2;
            const int c = (chunk & 3) * 8;
            *(uint4*)&Bs[r][c] =
                *(const uint4*)&Bt[(long long)(col0 + r) * D_FEAT + k0 + c];
        }
        __syncthreads();

        bf16x8 af[4], bfr[4];
        #pragma unroll
        for (int mi = 0; mi < 4; ++mi)
            af[mi] = *(const bf16x8*)&As[wm + mi * 16 + lm][lq * 8];
        #pragma unroll
        for (int ni = 0; ni < 4; ++ni)
            bfr[ni] = *(const bf16x8*)&Bs[wn + ni * 16 + lm][lq * 8];
        #pragma unroll
        for (int mi = 0; mi < 4; ++mi)
            #pragma unroll
            for (int ni = 0; ni < 4; ++ni)
                acc[mi][ni] = __builtin_amdgcn_mfma_f32_16x16x32_bf16(
                    af[mi], bfr[ni], acc[mi][ni], 0, 0, 0);
        __syncthreads();
    }

    // D layout: col = lane&15, row = (lane>>4)*4 + reg
    #pragma unroll
    for (int mi = 0; mi < 4; ++mi) {
        #pragma unroll
        for (int ni = 0; ni < 4; ++ni) {
            const int n = col0 + wn + ni * 16 + lm;
            const float b = bias[n];
            #pragma unroll
            for (int r = 0; r < 4; ++r) {
                const int m = row0 + wm + mi * 16 + lq * 4 + r;
                if (m < N_NODES)
                    C[(long long)m * D_FEAT + n] = acc[mi][ni][r] + b;
            }
        }
    }
}

// ---------------------------------------------------------------------------
// Fallback path (atomic f32 spmm + f32 GEMM) — only if ws too small.
// ---------------------------------------------------------------------------
__global__ __launch_bounds__(256) void spmm_scatter_kernel(
    const float* __restrict__ x, const int* __restrict__ edge_row,
    const int* __restrict__ edge_col, const float* __restrict__ edge_val,
    float* __restrict__ tmp)
{
    const long long gtid = (long long)blockIdx.x * blockDim.x + threadIdx.x;
    const int wave = (int)(gtid >> 6);
    const int lane = threadIdx.x & 63;
    if (wave >= TOT_E) return;
    const int g = wave / E_EDGES;
    const int row = edge_row[wave];
    const int col = edge_col[wave];
    const float val = edge_val[wave];
    atomicAdd(&tmp[(long long)row * D_FEAT + g * DG + lane],
              val * x[(long long)col * D_FEAT + g * DG + lane]);
}

__global__ __launch_bounds__(256) void gemm_bias_kernel(
    const float* __restrict__ A, const float* __restrict__ W,
    const float* __restrict__ bias, float* __restrict__ C)
{
    __shared__ float Asf[64][68];
    __shared__ float Wsf[64][68];
    const int tid = threadIdx.x;
    const int tx = tid & 15, ty = tid >> 4;
    const int row0 = blockIdx.x * 64, col0 = blockIdx.y * 64;
    float acc[4][4] = {};
    for (int k0 = 0; k0 < D_FEAT; k0 += 64) {
        #pragma unroll
        for (int l = 0; l < 4; ++l) {
            const int linear = tid + l * 256;
            const int ar = linear >> 4, ac = (linear & 15) << 2;
            float4 v = make_float4(0.f, 0.f, 0.f, 0.f);
            const int gr = row0 + ar;
            if (gr < N_NODES) v = *(const float4*)&A[(long long)gr * D_FEAT + k0 + ac];
            Asf[ac + 0][ar] = v.x; Asf[ac + 1][ar] = v.y;
            Asf[ac + 2][ar] = v.z; Asf[ac + 3][ar] = v.w;
        }
        #pragma unroll
        for (int l = 0; l < 4; ++l) {
            const int linear = tid + l * 256;
            const int wr = linear >> 4, wc = (linear & 15) << 2;
            *(float4*)&Wsf[wr][wc] =
                *(const float4*)&W[(long long)(k0 + wr) * D_FEAT + col0 + wc];
        }
        __syncthreads();
        #pragma unroll
        for (int k = 0; k < 64; ++k) {
            const float4 a4 = *(const float4*)&Asf[k][ty * 4];
            const float4 b4 = *(const float4*)&Wsf[k][tx * 4];
            const float a[4] = {a4.x, a4.y, a4.z, a4.w};
            const float b[4] = {b4.x, b4.y, b4.z, b4.w};
            #pragma unroll
            for (int i = 0; i < 4; ++i)
                #pragma unroll
                for (int j = 0; j < 4; ++j) acc[i][j] += a[i] * b[j];
        }
        __syncthreads();
    }
    const float4 b4 = *(const float4*)&bias[col0 + tx * 4];
    #pragma unroll
    for (int i = 0; i < 4; ++i) {
        const int gr = row0 + ty * 4 + i;
        if (gr >= N_NODES) continue;
        float4 v;
        v.x = acc[i][0] + b4.x; v.y = acc[i][1] + b4.y;
        v.z = acc[i][2] + b4.z; v.w = acc[i][3] + b4.w;
        *(float4*)&C[(long long)gr * D_FEAT + col0 + tx * 4] = v;
    }
}

// ---------------------------------------------------------------------------
extern "C" void kernel_launch(void* const* d_in, const int* in_sizes, int n_in,
                              void* d_out, int out_size, void* d_ws, size_t ws_size,
                              hipStream_t stream)
{
    const float* x        = (const float*)d_in[0];
    const int*   edge_row = (const int*)d_in[1];
    const int*   edge_col = (const int*)d_in[2];
    const float* edge_val = (const float*)d_in[3];
    const float* weight   = (const float*)d_in[4];
    const float* bias     = (const float*)d_in[5];
    float* out = (float*)d_out;

    char* p = (char*)d_ws;
    auto alloc = [&](size_t bytes) {
        char* r = p;
        p += (bytes + 255) & ~(size_t)255;
        return r;
    };
    unsigned short* xb   = (unsigned short*)alloc((size_t)N_NODES * D_FEAT * 2); // 25.6 MB
    unsigned short* tmpb = (unsigned short*)alloc((size_t)M_PAD * D_FEAT * 2);   // 25.6 MB
    unsigned short* Wt   = (unsigned short*)alloc((size_t)D_FEAT * D_FEAT * 2);  // 128 KB
    int* head = (int*)alloc((size_t)M_SEG * KSUB * sizeof(int));                 // 3.2 MB
    int* nxt  = (int*)alloc((size_t)TOT_E * sizeof(int));                        // 12.8 MB
    const size_t needed = (size_t)(p - (char*)d_ws);

    if (ws_size >= needed) {
        hipMemsetAsync(head, 0xFF, (size_t)M_SEG * KSUB * sizeof(int), stream);
        convert_x_kernel<<<(N_NODES * D_FEAT / 8 + 255) / 256, 256, 0, stream>>>(x, xb);
        convert_w_kernel<<<D_FEAT, D_FEAT, 0, stream>>>(weight, Wt);
        build_ll_kernel<<<(TOT_E + 255) / 256, 256, 0, stream>>>(edge_row, head, nxt);
        spmm_ll_kernel<<<M_SEG * 64 / 256, 256, 0, stream>>>(
            xb, edge_col, edge_val, head, nxt, tmpb);
        dim3 grid(M_PAD / 128, D_FEAT / 128);
        gemm_mfma_kernel<<<grid, 256, 0, stream>>>(tmpb, Wt, bias, out);
    } else {
        float* tmp = (float*)d_ws;
        hipMemsetAsync(tmp, 0, (size_t)N_NODES * D_FEAT * sizeof(float), stream);
        const long long total_threads = (long long)TOT_E * 64;
        spmm_scatter_kernel<<<(int)((total_threads + 255) / 256), 256, 0, stream>>>(
            x, edge_row, edge_col, edge_val, tmp);
        dim3 grid2((N_NODES + 63) / 64, D_FEAT / 64);
        gemm_bias_kernel<<<grid2, 256, 0, stream>>>(tmp, weight, bias, out);
    }
}